// Round 9
// baseline (118.223 us; speedup 1.0000x reference)
//
#include <hip/hip_runtime.h>
#include <hip/hip_bf16.h>

// FeatureAdaption on MI355X: offset = shape @ w_off (1x1), DCNv1 deform conv + ReLU.
// B=8, Cin=Cout=256, H=W=64, G=4, Cg=64, K=3, K2=9, NGK=36, NPIX=32768.
// kprep (koff first): pos (float2), channels-last bf16 xT[b][g][hw][c],
// fragment-major bf16 weights wF. kmain: 256o x 64px tile, 512 blocks (2/CU);
// packed rec tables (addrs+flags uint2, fy/fx float2); 2 taps per barrier with
// back-to-back MFMA and post-MFMA finishes (zero gather stall); weights
// global->register, wE/wO parity alternation; sV 4-buffer (32 KB).

#define NPIX 32768
#define NGK  36
#define HW   4096
#define WSTRIDE 16384   // u16 elements per tap in wF

typedef __attribute__((ext_vector_type(8))) short short8;
typedef __attribute__((ext_vector_type(4))) float f32x4;
typedef unsigned short u16;
typedef unsigned int u32;

__device__ __forceinline__ float bfu_lo(u32 u) {
    union { u32 u; float f; } cv; cv.u = u << 16; return cv.f;
}
__device__ __forceinline__ float bfu_hi(u32 u) {
    union { u32 u; float f; } cv; cv.u = u & 0xFFFF0000u; return cv.f;
}
__device__ __forceinline__ u16 f2bf(float f) {
    union { float f; u32 u; } cv;
    cv.f = f;
    u32 u = cv.u + 0x7FFFu + ((cv.u >> 16) & 1u);
    return (u16)(u >> 16);
}

// ---------------- kprep: koff (128) + kxt (2048) + kwb (2304) ----------------
__global__ __launch_bounds__(256) void kprep(const float* __restrict__ x,
                                             const float* __restrict__ shape,
                                             const float* __restrict__ w_off,
                                             const float* __restrict__ w_def,
                                             float2* __restrict__ pos,
                                             u16* __restrict__ xT,
                                             u16* __restrict__ wF) {
    __shared__ __align__(16) float smem[64 * 65];
    int tid = threadIdx.x;
    int blk = blockIdx.x;

    if (blk < 128) {
        // ---- koff: sampling positions float2 [gk][pix] (heavy -> first) ----
        float* wo = smem;  // 72*36 floats
        for (int i = tid; i < 72 * 36; i += 256) wo[i] = w_off[i];
        __syncthreads();
        int pix = blk * 256 + tid;
        int b = pix >> 12, hw = pix & 4095;
        int h = hw >> 6, w = hw & 63;
        float s[36];
#pragma unroll
        for (int i = 0; i < 36; ++i) s[i] = shape[((b * 36 + i) << 12) + hw];
        for (int gk = 0; gk < 36; ++gk) {
            float oy = 0.f, ox = 0.f;
            const float* wy = &wo[(gk * 2 + 0) * 36];
            const float* wx = &wo[(gk * 2 + 1) * 36];
#pragma unroll
            for (int i = 0; i < 36; ++i) { oy += s[i] * wy[i]; ox += s[i] * wx[i]; }
            int k = gk % 9;
            pos[gk * NPIX + pix] = make_float2(oy + (float)(k / 3 - 1) + (float)h,
                                               ox + (float)(k % 3 - 1) + (float)w);
        }
    } else if (blk < 2176) {
        // ---- kxt: x (B,256,H,W) fp32 -> xT[b][g][hw][c] bf16 ----
        float (*tile)[65] = (float (*)[65])smem;
        int xb  = blk - 128;
        int bg  = xb >> 6;
        int hw0 = (xb & 63) << 6;
        int hwo = tid & 63;
#pragma unroll
        for (int i = 0; i < 16; ++i) {
            int c = (tid >> 6) + (i << 2);
            tile[c][hwo] = x[((bg << 6) + c) * HW + hw0 + hwo];
        }
        __syncthreads();
        int hw = tid >> 2;
        int cb4 = (tid & 3) << 4;
        short8 r0, r1;
#pragma unroll
        for (int j = 0; j < 8; ++j) {
            r0[j] = (short)f2bf(tile[cb4 + j][hw]);
            r1[j] = (short)f2bf(tile[cb4 + 8 + j][hw]);
        }
        u16* dst = xT + (((bg << 12) + hw0 + hw) << 6) + cb4;
        *(short8*)dst = r0;
        *(short8*)(dst + 8) = r1;
    } else {
        // ---- kwb: fragment-major weights ----
        int idx = (blk - 2176) * 256 + tid;
        int c = idx & 63;
        int o = (idx >> 6) & 255;
        int gk = idx >> 14;
        int g = gk / 9, k = gk - g * 9;
        float v = w_def[((o << 8) + (g << 6) + c) * 9 + k];
        int wid = o >> 5, of = (o >> 4) & 1, olo = o & 15;
        int kc = c >> 5, cgran = (c >> 3) & 3, j = c & 7;
        int lane = (cgran << 4) | olo;
        wF[(gk << 14) + (wid << 11) + (of << 10) + (kc << 9) + (lane << 3) + j] = f2bf(v);
    }
}

// ---------------- main: fused sampling + MFMA GEMM + ReLU ----------------
struct Samp {
    short8 v00, v01, v10, v11;
    float w00, w01, w10, w11;
    int dst;
};

__device__ __forceinline__ Samp sample_issue_rec(uint2 ra, float2 fxy,
                                                 const u16* __restrict__ slab,
                                                 int sp, int sck) {
    Samp s;
    u32 rx = ra.x, ry = ra.y;
    int a00 = rx & 0xFFF, a01 = (rx >> 16) & 0xFFF;
    int a10 = ry & 0xFFF, a11 = (ry >> 16) & 0xFFF;
    const u16* base = slab + (sck << 3);
    s.v00 = *(const short8*)(base + (a00 << 6));
    s.v01 = *(const short8*)(base + (a01 << 6));
    s.v10 = *(const short8*)(base + (a10 << 6));
    s.v11 = *(const short8*)(base + (a11 << 6));
    float fy = fxy.x, fx = fxy.y;
    float wy0 = (rx & 0x1000u) ? (1.f - fy) : 0.f;   // exact 0/1 selects ->
    float wy1 = (rx & 0x2000u) ? fy : 0.f;           // products bit-identical
    float wx0 = (rx & 0x4000u) ? (1.f - fx) : 0.f;   // to stored-f32 weights
    float wx1 = (rx & 0x8000u) ? fx : 0.f;
    s.w00 = wy0 * wx0; s.w01 = wy0 * wx1;
    s.w10 = wy1 * wx0; s.w11 = wy1 * wx1;
    s.dst = (sp << 6) + ((sck ^ (sp & 7)) << 3);   // XOR-swizzled slot
    return s;
}

__device__ __forceinline__ void sample_finish(const Samp& s, u16* __restrict__ sVb) {
    union { short8 s8; u32 u[4]; } A, Bc, C, D;
    A.s8 = s.v00; Bc.s8 = s.v01; C.s8 = s.v10; D.s8 = s.v11;
    union { u32 u[4]; short8 s8; } R;
#pragma unroll
    for (int j = 0; j < 4; ++j) {
        float lo0 = fmaf(s.w00, bfu_lo(A.u[j]), s.w01 * bfu_lo(Bc.u[j]));
        float lo1 = fmaf(s.w10, bfu_lo(C.u[j]), s.w11 * bfu_lo(D.u[j]));
        float hi0 = fmaf(s.w00, bfu_hi(A.u[j]), s.w01 * bfu_hi(Bc.u[j]));
        float hi1 = fmaf(s.w10, bfu_hi(C.u[j]), s.w11 * bfu_hi(D.u[j]));
        __hip_bfloat162 pk = __float22bfloat162_rn(make_float2(lo0 + lo1, hi0 + hi1));
        union { __hip_bfloat162 b; u32 u; } cv; cv.b = pk;
        R.u[j] = cv.u;
    }
    *(short8*)(sVb + s.dst) = R.s8;
}

// MFMA over one tap: A-fragments (weights) in registers, B from sV LDS.
__device__ __forceinline__ void mfma_phase(const short8 wcur[4], const u16* __restrict__ Vb,
                                           int lane, f32x4 acc[2][4]) {
    __builtin_amdgcn_s_setprio(1);
#pragma unroll
    for (int kc = 0; kc < 2; ++kc) {
        int cs = ((kc << 5) + ((lane >> 4) << 3)) ^ ((lane & 7) << 3);
        short8 bfr[4];
#pragma unroll
        for (int pf = 0; pf < 4; ++pf)
            bfr[pf] = *(const short8*)(Vb + (((pf << 4) + (lane & 15)) << 6) + cs);
#pragma unroll
        for (int of = 0; of < 2; ++of)
#pragma unroll
            for (int pf = 0; pf < 4; ++pf)
                acc[of][pf] = __builtin_amdgcn_mfma_f32_16x16x32_bf16(
                    wcur[of * 2 + kc], bfr[pf], acc[of][pf], 0, 0, 0);
    }
    __builtin_amdgcn_s_setprio(0);
}

__global__ __launch_bounds__(512, 4) void kmain(
    const u16* __restrict__ xT,
    const float2* __restrict__ pos,
    const u16* __restrict__ wF, float* __restrict__ out)
{
    __shared__ __align__(16) u16 sV[4][4096];        // 4 x 8 KB sampled values
    __shared__ __align__(16) uint2 sRA[NGK * 64];    // addrs+flags, 18 KB
    __shared__ __align__(16) float2 sFX[NGK * 64];   // fy,fx, 18 KB

    int tid = threadIdx.x;
    int pixbase = blockIdx.x << 6;   // 64 pixels per block
    int b = pixbase >> 12;

    int sp = tid >> 3, sck = tid & 7;        // sampling roles: 64px x 8 chunks
    int lane = tid & 63, wid = tid >> 6;     // compute roles
    int o0 = wid << 5;                       // 8 o-slices of 32

    const u16* slabB = xT + ((size_t)b << 20);
    const u16* wlbase = wF + (wid << 11) + (lane << 3);

    f32x4 acc[2][4];
#pragma unroll
    for (int i = 0; i < 2; ++i)
#pragma unroll
        for (int j = 0; j < 4; ++j)
            acc[i][j] = (f32x4){0.f, 0.f, 0.f, 0.f};

    short8 wE[4], wO[4];

    // ---- prologue A: build packed rec tables ----
    for (int i = tid; i < NGK * 64; i += 512) {
        int gk = i >> 6, px = i & 63;
        float2 p = pos[gk * NPIX + pixbase + px];
        float y0f = floorf(p.x), x0f = floorf(p.y);
        float fy = p.x - y0f, fx = p.y - x0f;
        int y0 = (int)y0f, x0 = (int)x0f;
        int y1 = y0 + 1, x1 = x0 + 1;
        u32 flags = 0;
        if (y0 >= 0 && y0 < 64) flags |= 0x1000u;
        if (y1 >= 0 && y1 < 64) flags |= 0x2000u;
        if (x0 >= 0 && x0 < 64) flags |= 0x4000u;
        if (x1 >= 0 && x1 < 64) flags |= 0x8000u;
        int yc0 = min(max(y0, 0), 63), yc1 = min(max(y1, 0), 63);
        int xc0 = min(max(x0, 0), 63), xc1 = min(max(x1, 0), 63);
        u32 a00 = (u32)((yc0 << 6) | xc0), a01 = (u32)((yc0 << 6) | xc1);
        u32 a10 = (u32)((yc1 << 6) | xc0), a11 = (u32)((yc1 << 6) | xc1);
        sRA[i] = make_uint2(a00 | flags | (a01 << 16), a10 | (a11 << 16));
        sFX[i] = make_float2(fy, fx);
    }

    // weights tap 0 -> wE (independent of rec tables)
    wE[0] = *(const short8*)(wlbase);
    wE[1] = *(const short8*)(wlbase + 512);
    wE[2] = *(const short8*)(wlbase + 1024);
    wE[3] = *(const short8*)(wlbase + 1536);
    __syncthreads();   // rec tables ready

    // ---- prologue B: sample + finish taps 0,1 -> sV[0], sV[1] ----
    {
        Samp s0 = sample_issue_rec(sRA[sp], sFX[sp], slabB, sp, sck);
        sample_finish(s0, sV[0]);
        Samp s1 = sample_issue_rec(sRA[64 + sp], sFX[64 + sp], slabB, sp, sck);
        sample_finish(s1, sV[1]);
    }
    __syncthreads();

    // ---- 17 phases, 2 taps each: taps 0..33, prefetch through tap 35 ----
    for (int p = 0; p < 17; ++p) {
        int t0 = p << 1;
        int cur = (p & 1) << 1, nxt = cur ^ 2;

        // odd weights for MFMA(t0+1)
        const u16* wop = wlbase + (t0 + 1) * WSTRIDE;
        wO[0] = *(const short8*)(wop);
        wO[1] = *(const short8*)(wop + 512);
        wO[2] = *(const short8*)(wop + 1024);
        wO[3] = *(const short8*)(wop + 1536);

        // issue gathers for taps t0+2, t0+3 (finished after both MFMAs)
        int ta = t0 + 2, tb = t0 + 3;
        Samp sA = sample_issue_rec(sRA[(ta << 6) + sp], sFX[(ta << 6) + sp],
                                   slabB + ((ta / 9) << 18), sp, sck);
        Samp sB = sample_issue_rec(sRA[(tb << 6) + sp], sFX[(tb << 6) + sp],
                                   slabB + ((tb / 9) << 18), sp, sck);
        __builtin_amdgcn_sched_barrier(0);

        mfma_phase(wE, &sV[cur][0], lane, acc);

        // even weights for next phase (after wE's last use)
        const u16* wep = wlbase + (t0 + 2) * WSTRIDE;
        wE[0] = *(const short8*)(wep);
        wE[1] = *(const short8*)(wep + 512);
        wE[2] = *(const short8*)(wep + 1024);
        wE[3] = *(const short8*)(wep + 1536);
        __builtin_amdgcn_sched_barrier(0);

        mfma_phase(wO, &sV[cur + 1][0], lane, acc);

        sample_finish(sA, &sV[nxt][0]);
        sample_finish(sB, &sV[nxt + 1][0]);
        __syncthreads();
    }

    // ---- tail: taps 34 (sV[2]), 35 (sV[3]) ----
    {
        const u16* wop = wlbase + 35 * WSTRIDE;
        wO[0] = *(const short8*)(wop);
        wO[1] = *(const short8*)(wop + 512);
        wO[2] = *(const short8*)(wop + 1024);
        wO[3] = *(const short8*)(wop + 1536);
        __builtin_amdgcn_sched_barrier(0);
        mfma_phase(wE, &sV[2][0], lane, acc);   // tap 34 (wE loaded in p=16)
        mfma_phase(wO, &sV[3][0], lane, acc);   // tap 35
    }

    // ---- epilogue: ReLU + store ----
    int hwb = pixbase & 4095;
    int obase = (b << 8) + o0 + ((lane >> 4) << 2);
#pragma unroll
    for (int of = 0; of < 2; ++of) {
#pragma unroll
        for (int pf = 0; pf < 4; ++pf) {
            float* op = out + ((obase + (of << 4)) << 12) + hwb + (pf << 4) + (lane & 15);
#pragma unroll
            for (int r = 0; r < 4; ++r)
                op[r << 12] = fmaxf(acc[of][pf][r], 0.f);
        }
    }
}

extern "C" void kernel_launch(void* const* d_in, const int* in_sizes, int n_in,
                              void* d_out, int out_size, void* d_ws, size_t ws_size,
                              hipStream_t stream) {
    const float* x     = (const float*)d_in[0];
    const float* shape = (const float*)d_in[1];
    const float* w_off = (const float*)d_in[2];
    const float* w_def = (const float*)d_in[3];
    float* out = (float*)d_out;

    float2* pos = (float2*)d_ws;                      // 36*32768 float2 = 9.4 MB
    u16*    wF  = (u16*)(pos + NGK * NPIX);           // 36*256*64 bf16 = 1.18 MB
    u16*    xT  = wF + NGK * 256 * 64;                // 8*4*4096*64 bf16 = 16.8 MB

    kprep<<<4480, 256, 0, stream>>>(x, shape, w_off, w_def, pos, xT, wF);
    kmain<<<NPIX / 64, 512, 0, stream>>>(xT, pos, wF, out);
}

// Round 10
// 79.722 us; speedup vs baseline: 1.4829x; 1.4829x over previous
//
#include <hip/hip_runtime.h>
#include <hip/hip_bf16.h>

// FeatureAdaption on MI355X: offset = shape @ w_off (1x1), DCNv1 deform conv + ReLU.
// B=8, Cin=Cout=256, H=W=64, G=4, Cg=64, K=3, K2=9, NGK=36, NPIX=32768.
// kprep: channels-last bf16 xT[b][g][hw][c] + fragment-major bf16 weights wF.
// kmain: 256o x 64px tile, 512 blocks (2/CU). Prologue computes offsets in-block
// (wave-uniform w_off rows -> scalar loads), packed rec tables in LDS.
// Body: 17 phases x 2 taps, ONE Samp live at a time, 18 barriers total;
// weights global->register (wE/wO), sV 4-buffer (32 KB).

#define NPIX 32768
#define NGK  36
#define HW   4096
#define WSTRIDE 16384   // u16 elements per tap in wF

typedef __attribute__((ext_vector_type(8))) short short8;
typedef __attribute__((ext_vector_type(4))) float f32x4;
typedef unsigned short u16;
typedef unsigned int u32;

__device__ __forceinline__ float bfu_lo(u32 u) {
    union { u32 u; float f; } cv; cv.u = u << 16; return cv.f;
}
__device__ __forceinline__ float bfu_hi(u32 u) {
    union { u32 u; float f; } cv; cv.u = u & 0xFFFF0000u; return cv.f;
}
__device__ __forceinline__ u16 f2bf(float f) {
    union { float f; u32 u; } cv;
    cv.f = f;
    u32 u = cv.u + 0x7FFFu + ((cv.u >> 16) & 1u);
    return (u16)(u >> 16);
}

// ---------------- kprep: kxt (2048) + kwb (2304) ----------------
__global__ __launch_bounds__(256) void kprep(const float* __restrict__ x,
                                             const float* __restrict__ w_def,
                                             u16* __restrict__ xT,
                                             u16* __restrict__ wF) {
    __shared__ __align__(16) float smem[64 * 65];
    int tid = threadIdx.x;
    int blk = blockIdx.x;

    if (blk < 2048) {
        // ---- kxt: x (B,256,H,W) fp32 -> xT[b][g][hw][c] bf16 ----
        float (*tile)[65] = (float (*)[65])smem;
        int bg  = blk >> 6;
        int hw0 = (blk & 63) << 6;
        int hwo = tid & 63;
#pragma unroll
        for (int i = 0; i < 16; ++i) {
            int c = (tid >> 6) + (i << 2);
            tile[c][hwo] = x[((bg << 6) + c) * HW + hw0 + hwo];
        }
        __syncthreads();
        int hw = tid >> 2;
        int cb4 = (tid & 3) << 4;
        short8 r0, r1;
#pragma unroll
        for (int j = 0; j < 8; ++j) {
            r0[j] = (short)f2bf(tile[cb4 + j][hw]);
            r1[j] = (short)f2bf(tile[cb4 + 8 + j][hw]);
        }
        u16* dst = xT + (((bg << 12) + hw0 + hw) << 6) + cb4;
        *(short8*)dst = r0;
        *(short8*)(dst + 8) = r1;
    } else {
        // ---- kwb: fragment-major weights ----
        // (gk,o,c) -> wF[gk][wid=o>>5][of=(o>>4)&1][kc=c>>5][lane=((c>>3)&3)<<4|(o&15)][j=c&7]
        int idx = (blk - 2048) * 256 + tid;
        int c = idx & 63;
        int o = (idx >> 6) & 255;
        int gk = idx >> 14;
        int g = gk / 9, k = gk - g * 9;
        float v = w_def[((o << 8) + (g << 6) + c) * 9 + k];
        int wid = o >> 5, of = (o >> 4) & 1, olo = o & 15;
        int kc = c >> 5, cgran = (c >> 3) & 3, j = c & 7;
        int lane = (cgran << 4) | olo;
        wF[(gk << 14) + (wid << 11) + (of << 10) + (kc << 9) + (lane << 3) + j] = f2bf(v);
    }
}

// ---------------- main: fused offsets + sampling + MFMA GEMM + ReLU ----------------
struct Samp {
    short8 v00, v01, v10, v11;
    float w00, w01, w10, w11;
    int dst;
};

__device__ __forceinline__ Samp sample_issue_rec(uint2 ra, float2 fxy,
                                                 const u16* __restrict__ slab,
                                                 int sp, int sck) {
    Samp s;
    u32 rx = ra.x, ry = ra.y;
    int a00 = rx & 0xFFF, a01 = (rx >> 16) & 0xFFF;
    int a10 = ry & 0xFFF, a11 = (ry >> 16) & 0xFFF;
    const u16* base = slab + (sck << 3);
    s.v00 = *(const short8*)(base + (a00 << 6));
    s.v01 = *(const short8*)(base + (a01 << 6));
    s.v10 = *(const short8*)(base + (a10 << 6));
    s.v11 = *(const short8*)(base + (a11 << 6));
    float fy = fxy.x, fx = fxy.y;
    float wy0 = (rx & 0x1000u) ? (1.f - fy) : 0.f;   // exact 0/1 selects ->
    float wy1 = (rx & 0x2000u) ? fy : 0.f;           // products bit-identical
    float wx0 = (rx & 0x4000u) ? (1.f - fx) : 0.f;
    float wx1 = (rx & 0x8000u) ? fx : 0.f;
    s.w00 = wy0 * wx0; s.w01 = wy0 * wx1;
    s.w10 = wy1 * wx0; s.w11 = wy1 * wx1;
    s.dst = (sp << 6) + ((sck ^ (sp & 7)) << 3);   // XOR-swizzled slot
    return s;
}

__device__ __forceinline__ void sample_finish(const Samp& s, u16* __restrict__ sVb) {
    union { short8 s8; u32 u[4]; } A, Bc, C, D;
    A.s8 = s.v00; Bc.s8 = s.v01; C.s8 = s.v10; D.s8 = s.v11;
    union { u32 u[4]; short8 s8; } R;
#pragma unroll
    for (int j = 0; j < 4; ++j) {
        float lo0 = fmaf(s.w00, bfu_lo(A.u[j]), s.w01 * bfu_lo(Bc.u[j]));
        float lo1 = fmaf(s.w10, bfu_lo(C.u[j]), s.w11 * bfu_lo(D.u[j]));
        float hi0 = fmaf(s.w00, bfu_hi(A.u[j]), s.w01 * bfu_hi(Bc.u[j]));
        float hi1 = fmaf(s.w10, bfu_hi(C.u[j]), s.w11 * bfu_hi(D.u[j]));
        __hip_bfloat162 pk = __float22bfloat162_rn(make_float2(lo0 + lo1, hi0 + hi1));
        union { __hip_bfloat162 b; u32 u; } cv; cv.b = pk;
        R.u[j] = cv.u;
    }
    *(short8*)(sVb + s.dst) = R.s8;
}

__device__ __forceinline__ void mfma_phase(const short8 wcur[4], const u16* __restrict__ Vb,
                                           int lane, f32x4 acc[2][4]) {
    __builtin_amdgcn_s_setprio(1);
#pragma unroll
    for (int kc = 0; kc < 2; ++kc) {
        int cs = ((kc << 5) + ((lane >> 4) << 3)) ^ ((lane & 7) << 3);
        short8 bfr[4];
#pragma unroll
        for (int pf = 0; pf < 4; ++pf)
            bfr[pf] = *(const short8*)(Vb + (((pf << 4) + (lane & 15)) << 6) + cs);
#pragma unroll
        for (int of = 0; of < 2; ++of)
#pragma unroll
            for (int pf = 0; pf < 4; ++pf)
                acc[of][pf] = __builtin_amdgcn_mfma_f32_16x16x32_bf16(
                    wcur[of * 2 + kc], bfr[pf], acc[of][pf], 0, 0, 0);
    }
    __builtin_amdgcn_s_setprio(0);
}

__global__ __launch_bounds__(512, 4) void kmain(
    const u16* __restrict__ xT,
    const float* __restrict__ shape,
    const float* __restrict__ w_off,
    const u16* __restrict__ wF, float* __restrict__ out)
{
    __shared__ __align__(16) u16 sV[4][4096];        // 4 x 8 KB sampled values
    __shared__ __align__(16) uint2 sRA[NGK * 64];    // addrs+flags, 18 KB
    __shared__ __align__(16) float2 sFX[NGK * 64];   // fy,fx, 18 KB

    int tid = threadIdx.x;
    int pixbase = blockIdx.x << 6;   // 64 pixels per block
    int b = pixbase >> 12;

    int sp = tid >> 3, sck = tid & 7;        // sampling roles: 64px x 8 chunks
    int lane = tid & 63, wid = tid >> 6;     // compute roles
    int o0 = wid << 5;                       // 8 o-slices of 32

    const u16* slabB = xT + ((size_t)b << 20);
    const u16* wlbase = wF + (wid << 11) + (lane << 3);

    f32x4 acc[2][4];
#pragma unroll
    for (int i = 0; i < 2; ++i)
#pragma unroll
        for (int j = 0; j < 4; ++j)
            acc[i][j] = (f32x4){0.f, 0.f, 0.f, 0.f};

    short8 wE[4], wO[4];

    // ---- prologue A: compute offsets + rec tables in-block ----
    // lane px = tid&63; wave (slot) owns gk = slot + 8j. w_off rows are
    // wave-uniform -> scalar loads. Same FMA order as the old koff kernel.
    {
        int px = tid & 63;
        int hw = (pixbase & 4095) + px;
        int h = hw >> 6, w = hw & 63;
        float s[36];
#pragma unroll
        for (int i = 0; i < 36; ++i) s[i] = shape[((b * 36 + i) << 12) + hw];
        int uslot = __builtin_amdgcn_readfirstlane(wid);
#pragma unroll
        for (int j = 0; j < 5; ++j) {
            int gk = uslot + (j << 3);
            if (gk < 36) {
                const float* wy = w_off + (gk * 2) * 36;
                const float* wx = wy + 36;
                float oy = 0.f, ox = 0.f;
#pragma unroll
                for (int i = 0; i < 36; ++i) { oy += s[i] * wy[i]; ox += s[i] * wx[i]; }
                int k = gk % 9;
                float py = oy + (float)(k / 3 - 1) + (float)h;
                float pxx = ox + (float)(k % 3 - 1) + (float)w;
                float y0f = floorf(py), x0f = floorf(pxx);
                float fy = py - y0f, fx = pxx - x0f;
                int y0 = (int)y0f, x0 = (int)x0f;
                int y1 = y0 + 1, x1 = x0 + 1;
                u32 flags = 0;
                if (y0 >= 0 && y0 < 64) flags |= 0x1000u;
                if (y1 >= 0 && y1 < 64) flags |= 0x2000u;
                if (x0 >= 0 && x0 < 64) flags |= 0x4000u;
                if (x1 >= 0 && x1 < 64) flags |= 0x8000u;
                int yc0 = min(max(y0, 0), 63), yc1 = min(max(y1, 0), 63);
                int xc0 = min(max(x0, 0), 63), xc1 = min(max(x1, 0), 63);
                u32 a00 = (u32)((yc0 << 6) | xc0), a01 = (u32)((yc0 << 6) | xc1);
                u32 a10 = (u32)((yc1 << 6) | xc0), a11 = (u32)((yc1 << 6) | xc1);
                int idx = (gk << 6) + px;
                sRA[idx] = make_uint2(a00 | flags | (a01 << 16), a10 | (a11 << 16));
                sFX[idx] = make_float2(fy, fx);
            }
        }
    }

    // weights tap 0 -> wE (independent of rec tables)
    wE[0] = *(const short8*)(wlbase);
    wE[1] = *(const short8*)(wlbase + 512);
    wE[2] = *(const short8*)(wlbase + 1024);
    wE[3] = *(const short8*)(wlbase + 1536);
    __syncthreads();   // rec tables ready

    // ---- prologue B: sample + finish taps 0,1 -> sV[0], sV[1] ----
    {
        Samp s0 = sample_issue_rec(sRA[sp], sFX[sp], slabB, sp, sck);
        sample_finish(s0, sV[0]);
        Samp s1 = sample_issue_rec(sRA[64 + sp], sFX[64 + sp], slabB, sp, sck);
        sample_finish(s1, sV[1]);
    }
    __syncthreads();

    // ---- 17 phases x 2 taps (taps 0..33), ONE Samp live at a time ----
    for (int p = 0; p < 17; ++p) {
        int t0 = p << 1;
        int cur = (p & 1) << 1, nxt = cur ^ 2;
        int ta = t0 + 2, tb = t0 + 3;

        // wO for MFMA(t0+1)
        const u16* wop = wlbase + (t0 + 1) * WSTRIDE;
        wO[0] = *(const short8*)(wop);
        wO[1] = *(const short8*)(wop + 512);
        wO[2] = *(const short8*)(wop + 1024);
        wO[3] = *(const short8*)(wop + 1536);

        // issue gathers tap ta; finish after MFMA(t0)
        Samp sA = sample_issue_rec(sRA[(ta << 6) + sp], sFX[(ta << 6) + sp],
                                   slabB + ((ta / 9) << 18), sp, sck);
        __builtin_amdgcn_sched_barrier(0);
        mfma_phase(wE, &sV[cur][0], lane, acc);
        sample_finish(sA, &sV[nxt][0]);

        // wE for next phase (tap t0+2)
        const u16* wep = wlbase + (t0 + 2) * WSTRIDE;
        wE[0] = *(const short8*)(wep);
        wE[1] = *(const short8*)(wep + 512);
        wE[2] = *(const short8*)(wep + 1024);
        wE[3] = *(const short8*)(wep + 1536);

        // issue gathers tap tb; finish after MFMA(t0+1)
        Samp sB = sample_issue_rec(sRA[(tb << 6) + sp], sFX[(tb << 6) + sp],
                                   slabB + ((tb / 9) << 18), sp, sck);
        __builtin_amdgcn_sched_barrier(0);
        mfma_phase(wO, &sV[cur + 1][0], lane, acc);
        sample_finish(sB, &sV[nxt + 1][0]);

        __syncthreads();
    }

    // ---- tail: taps 34 (sV[2]), 35 (sV[3]); wE holds tap 34 from p=16 ----
    {
        const u16* wop = wlbase + 35 * WSTRIDE;
        wO[0] = *(const short8*)(wop);
        wO[1] = *(const short8*)(wop + 512);
        wO[2] = *(const short8*)(wop + 1024);
        wO[3] = *(const short8*)(wop + 1536);
        __builtin_amdgcn_sched_barrier(0);
        mfma_phase(wE, &sV[2][0], lane, acc);
        mfma_phase(wO, &sV[3][0], lane, acc);
    }

    // ---- epilogue: ReLU + store ----
    int hwb = pixbase & 4095;
    int obase = (b << 8) + o0 + ((lane >> 4) << 2);
#pragma unroll
    for (int of = 0; of < 2; ++of) {
#pragma unroll
        for (int pf = 0; pf < 4; ++pf) {
            float* op = out + ((obase + (of << 4)) << 12) + hwb + (pf << 4) + (lane & 15);
#pragma unroll
            for (int r = 0; r < 4; ++r)
                op[r << 12] = fmaxf(acc[of][pf][r], 0.f);
        }
    }
}

extern "C" void kernel_launch(void* const* d_in, const int* in_sizes, int n_in,
                              void* d_out, int out_size, void* d_ws, size_t ws_size,
                              hipStream_t stream) {
    const float* x     = (const float*)d_in[0];
    const float* shape = (const float*)d_in[1];
    const float* w_off = (const float*)d_in[2];
    const float* w_def = (const float*)d_in[3];
    float* out = (float*)d_out;

    u16* wF = (u16*)d_ws;                 // 36*256*64 bf16 = 1.18 MB
    u16* xT = wF + NGK * 256 * 64;        // 8*4*4096*64 bf16 = 16.8 MB

    kprep<<<4352, 256, 0, stream>>>(x, w_def, xT, wF);
    kmain<<<NPIX / 64, 512, 0, stream>>>(xT, shape, w_off, wF, out);
}

// Round 11
// 76.804 us; speedup vs baseline: 1.5393x; 1.0380x over previous
//
#include <hip/hip_runtime.h>
#include <hip/hip_bf16.h>

// FeatureAdaption on MI355X: offset = shape @ w_off (1x1), DCNv1 deform conv + ReLU.
// B=8, Cin=Cout=256, H=W=64, G=4, Cg=64, K=3, K2=9, NGK=36, NPIX=32768.
// kprep: channels-last bf16 xT[b][g][hw][c] + fragment-major bf16 weights wF.
// kmain: 256o x 64px tile, 512 blocks (2/CU). Prologue A computes offsets
// in-block (wave-uniform w_off rows -> scalar loads) + rec tables (uint2 addrs,
// float4 exact weights). Body: R8's proven 1-tap-per-barrier pipeline
// (wC/wN weight alternation -- never rewrite a just-used MFMA source set).

#define NPIX 32768
#define NGK  36
#define HW   4096
#define WSTRIDE 16384   // u16 elements per tap in wF

typedef __attribute__((ext_vector_type(8))) short short8;
typedef __attribute__((ext_vector_type(4))) float f32x4;
typedef unsigned short u16;
typedef unsigned int u32;

__device__ __forceinline__ float bfu_lo(u32 u) {
    union { u32 u; float f; } cv; cv.u = u << 16; return cv.f;
}
__device__ __forceinline__ float bfu_hi(u32 u) {
    union { u32 u; float f; } cv; cv.u = u & 0xFFFF0000u; return cv.f;
}
__device__ __forceinline__ u16 f2bf(float f) {
    union { float f; u32 u; } cv;
    cv.f = f;
    u32 u = cv.u + 0x7FFFu + ((cv.u >> 16) & 1u);
    return (u16)(u >> 16);
}

// ---------------- kprep: kxt (2048) + kwb (2304) ----------------
__global__ __launch_bounds__(256) void kprep(const float* __restrict__ x,
                                             const float* __restrict__ w_def,
                                             u16* __restrict__ xT,
                                             u16* __restrict__ wF) {
    __shared__ __align__(16) float smem[64 * 65];
    int tid = threadIdx.x;
    int blk = blockIdx.x;

    if (blk < 2048) {
        // ---- kxt: x (B,256,H,W) fp32 -> xT[b][g][hw][c] bf16 ----
        float (*tile)[65] = (float (*)[65])smem;
        int bg  = blk >> 6;
        int hw0 = (blk & 63) << 6;
        int hwo = tid & 63;
#pragma unroll
        for (int i = 0; i < 16; ++i) {
            int c = (tid >> 6) + (i << 2);
            tile[c][hwo] = x[((bg << 6) + c) * HW + hw0 + hwo];
        }
        __syncthreads();
        int hw = tid >> 2;
        int cb4 = (tid & 3) << 4;
        short8 r0, r1;
#pragma unroll
        for (int j = 0; j < 8; ++j) {
            r0[j] = (short)f2bf(tile[cb4 + j][hw]);
            r1[j] = (short)f2bf(tile[cb4 + 8 + j][hw]);
        }
        u16* dst = xT + (((bg << 12) + hw0 + hw) << 6) + cb4;
        *(short8*)dst = r0;
        *(short8*)(dst + 8) = r1;
    } else {
        // ---- kwb: fragment-major weights ----
        // (gk,o,c) -> wF[gk][wid=o>>5][of=(o>>4)&1][kc=c>>5][lane=((c>>3)&3)<<4|(o&15)][j=c&7]
        int idx = (blk - 2048) * 256 + tid;
        int c = idx & 63;
        int o = (idx >> 6) & 255;
        int gk = idx >> 14;
        int g = gk / 9, k = gk - g * 9;
        float v = w_def[((o << 8) + (g << 6) + c) * 9 + k];
        int wid = o >> 5, of = (o >> 4) & 1, olo = o & 15;
        int kc = c >> 5, cgran = (c >> 3) & 3, j = c & 7;
        int lane = (cgran << 4) | olo;
        wF[(gk << 14) + (wid << 11) + (of << 10) + (kc << 9) + (lane << 3) + j] = f2bf(v);
    }
}

// ---------------- main: fused offsets + sampling + MFMA GEMM + ReLU ----------------
struct Samp {
    short8 v00, v01, v10, v11;
    float w00, w01, w10, w11;
    int dst;
};

__device__ __forceinline__ Samp sample_issue_rec(uint2 ra, float4 rw,
                                                 const u16* __restrict__ slab,
                                                 int sp, int sck) {
    Samp s;
    int a00 = ra.x & 0xFFFF, a01 = ra.x >> 16;
    int a10 = ra.y & 0xFFFF, a11 = ra.y >> 16;
    const u16* base = slab + (sck << 3);
    s.v00 = *(const short8*)(base + (a00 << 6));
    s.v01 = *(const short8*)(base + (a01 << 6));
    s.v10 = *(const short8*)(base + (a10 << 6));
    s.v11 = *(const short8*)(base + (a11 << 6));
    s.w00 = rw.x; s.w01 = rw.y; s.w10 = rw.z; s.w11 = rw.w;
    s.dst = (sp << 6) + ((sck ^ (sp & 7)) << 3);   // XOR-swizzled slot
    return s;
}

__device__ __forceinline__ void sample_finish(const Samp& s, u16* __restrict__ sVb) {
    union { short8 s8; u32 u[4]; } A, Bc, C, D;
    A.s8 = s.v00; Bc.s8 = s.v01; C.s8 = s.v10; D.s8 = s.v11;
    union { u32 u[4]; short8 s8; } R;
#pragma unroll
    for (int j = 0; j < 4; ++j) {
        float lo0 = fmaf(s.w00, bfu_lo(A.u[j]), s.w01 * bfu_lo(Bc.u[j]));
        float lo1 = fmaf(s.w10, bfu_lo(C.u[j]), s.w11 * bfu_lo(D.u[j]));
        float hi0 = fmaf(s.w00, bfu_hi(A.u[j]), s.w01 * bfu_hi(Bc.u[j]));
        float hi1 = fmaf(s.w10, bfu_hi(C.u[j]), s.w11 * bfu_hi(D.u[j]));
        __hip_bfloat162 pk = __float22bfloat162_rn(make_float2(lo0 + lo1, hi0 + hi1));
        union { __hip_bfloat162 b; u32 u; } cv; cv.b = pk;
        R.u[j] = cv.u;
    }
    *(short8*)(sVb + s.dst) = R.s8;
}

__device__ __forceinline__ void mfma_phase(const short8 wcur[4], const u16* __restrict__ Vb,
                                           int lane, f32x4 acc[2][4]) {
    __builtin_amdgcn_s_setprio(1);
#pragma unroll
    for (int kc = 0; kc < 2; ++kc) {
        int cs = ((kc << 5) + ((lane >> 4) << 3)) ^ ((lane & 7) << 3);
        short8 bfr[4];
#pragma unroll
        for (int pf = 0; pf < 4; ++pf)
            bfr[pf] = *(const short8*)(Vb + (((pf << 4) + (lane & 15)) << 6) + cs);
#pragma unroll
        for (int of = 0; of < 2; ++of)
#pragma unroll
            for (int pf = 0; pf < 4; ++pf)
                acc[of][pf] = __builtin_amdgcn_mfma_f32_16x16x32_bf16(
                    wcur[of * 2 + kc], bfr[pf], acc[of][pf], 0, 0, 0);
    }
    __builtin_amdgcn_s_setprio(0);
}

__global__ __launch_bounds__(512, 4) void kmain(
    const u16* __restrict__ xT,
    const float* __restrict__ shape,
    const float* __restrict__ w_off,
    const u16* __restrict__ wF, float* __restrict__ out)
{
    __shared__ __align__(16) u16 sV[2][4096];        // 2 x 8 KB sampled values
    __shared__ __align__(16) uint2 sRA[NGK * 64];    // packed corner addrs, 18 KB
    __shared__ __align__(16) float4 sRW[NGK * 64];   // corner weights f32, 36 KB

    int tid = threadIdx.x;
    int pixbase = blockIdx.x << 6;   // 64 pixels per block
    int b = pixbase >> 12;

    int sp = tid >> 3, sck = tid & 7;        // sampling roles: 64px x 8 chunks
    int lane = tid & 63, wid = tid >> 6;     // compute roles
    int o0 = wid << 5;                       // 8 o-slices of 32

    const u16* slabB = xT + ((size_t)b << 20);
    const u16* wlbase = wF + (wid << 11) + (lane << 3);

    f32x4 acc[2][4];
#pragma unroll
    for (int i = 0; i < 2; ++i)
#pragma unroll
        for (int j = 0; j < 4; ++j)
            acc[i][j] = (f32x4){0.f, 0.f, 0.f, 0.f};

    short8 wC[4], wN[4];
    Samp s;

    // ---- prologue A: compute offsets + rec tables in-block ----
    // lane px = tid&63; wave (slot) owns gk = slot + 8j. w_off rows are
    // wave-uniform -> scalar loads. Same FMA order as the old koff kernel.
    {
        int px = tid & 63;
        int hw = (pixbase & 4095) + px;
        int h = hw >> 6, w = hw & 63;
        float sv[36];
#pragma unroll
        for (int i = 0; i < 36; ++i) sv[i] = shape[((b * 36 + i) << 12) + hw];
        int uslot = __builtin_amdgcn_readfirstlane(wid);
#pragma unroll
        for (int j = 0; j < 5; ++j) {
            int gk = uslot + (j << 3);
            if (gk < 36) {
                const float* wy = w_off + (gk * 2) * 36;
                const float* wx = wy + 36;
                float oy = 0.f, ox = 0.f;
#pragma unroll
                for (int i = 0; i < 36; ++i) { oy += sv[i] * wy[i]; ox += sv[i] * wx[i]; }
                int k = gk % 9;
                float py = oy + (float)(k / 3 - 1) + (float)h;
                float pxx = ox + (float)(k % 3 - 1) + (float)w;
                float y0f = floorf(py), x0f = floorf(pxx);
                float fy = py - y0f, fx = pxx - x0f;
                int y0 = (int)y0f, x0 = (int)x0f;
                int y1 = y0 + 1, x1 = x0 + 1;
                float vy0 = (y0 >= 0 && y0 < 64) ? 1.f : 0.f;
                float vy1 = (y1 >= 0 && y1 < 64) ? 1.f : 0.f;
                float vx0 = (x0 >= 0 && x0 < 64) ? 1.f : 0.f;
                float vx1 = (x1 >= 0 && x1 < 64) ? 1.f : 0.f;
                float w00 = (1.f - fy) * (1.f - fx) * vy0 * vx0;
                float w01 = (1.f - fy) * fx * vy0 * vx1;
                float w10 = fy * (1.f - fx) * vy1 * vx0;
                float w11 = fy * fx * vy1 * vx1;
                int yc0 = min(max(y0, 0), 63), yc1 = min(max(y1, 0), 63);
                int xc0 = min(max(x0, 0), 63), xc1 = min(max(x1, 0), 63);
                u32 A = (u32)((yc0 << 6) | xc0) | ((u32)((yc0 << 6) | xc1) << 16);
                u32 Bp = (u32)((yc1 << 6) | xc0) | ((u32)((yc1 << 6) | xc1) << 16);
                int idx = (gk << 6) + px;
                sRA[idx] = make_uint2(A, Bp);
                sRW[idx] = make_float4(w00, w01, w10, w11);
            }
        }
    }

    // weights tap 0 -> wC (independent of rec tables)
    wC[0] = *(const short8*)(wlbase);
    wC[1] = *(const short8*)(wlbase + 512);
    wC[2] = *(const short8*)(wlbase + 1024);
    wC[3] = *(const short8*)(wlbase + 1536);
    __syncthreads();   // rec tables ready

    // ---- prologue B: sample + finish tap 0 ----
    {
        Samp s0 = sample_issue_rec(sRA[sp], sRW[sp], slabB, sp, sck);
        sample_finish(s0, sV[0]);
    }
    __syncthreads();

    // body(t): weights(t+1)->WNXT; rec(t+1) from LDS; issue gathers(t+1);
    // MFMA(t) with WCUR + sV[t&1]; finish(t+1) -> sV[nb]; barrier.
#define TAP_BODY(T, WCUR, WNXT)                                                  \
    {                                                                            \
        const int t_ = (T);                                                      \
        const u16* wn = wlbase + (t_ + 1) * WSTRIDE;                             \
        WNXT[0] = *(const short8*)(wn);                                          \
        WNXT[1] = *(const short8*)(wn + 512);                                    \
        WNXT[2] = *(const short8*)(wn + 1024);                                   \
        WNXT[3] = *(const short8*)(wn + 1536);                                   \
        s = sample_issue_rec(sRA[((t_ + 1) << 6) + sp], sRW[((t_ + 1) << 6) + sp], \
                             slabB + (((t_ + 1) / 9) << 18), sp, sck);           \
        __builtin_amdgcn_sched_barrier(0);                                       \
        mfma_phase(WCUR, &sV[t_ & 1][0], lane, acc);                             \
        sample_finish(s, &sV[(t_ & 1) ^ 1][0]);                                  \
        __syncthreads();                                                         \
    }

    for (int t = 0; t < 34; t += 2) {
        TAP_BODY(t,     wC, wN)
        TAP_BODY(t + 1, wN, wC)
    }
#undef TAP_BODY

    // ---- t=34: uses wC; prefetch tap35 -> wN; finish tap35 samples ----
    {
        const u16* wn = wlbase + 35 * WSTRIDE;
        wN[0] = *(const short8*)(wn);
        wN[1] = *(const short8*)(wn + 512);
        wN[2] = *(const short8*)(wn + 1024);
        wN[3] = *(const short8*)(wn + 1536);
        s = sample_issue_rec(sRA[(35 << 6) + sp], sRW[(35 << 6) + sp],
                             slabB + (3 << 18), sp, sck);
        __builtin_amdgcn_sched_barrier(0);
        mfma_phase(wC, &sV[0][0], lane, acc);
        sample_finish(s, &sV[1][0]);
        __syncthreads();
    }
    // ---- t=35 ----
    mfma_phase(wN, &sV[1][0], lane, acc);

    // ---- epilogue: ReLU + store ----
    int hwb = pixbase & 4095;
    int obase = (b << 8) + o0 + ((lane >> 4) << 2);
#pragma unroll
    for (int of = 0; of < 2; ++of) {
#pragma unroll
        for (int pf = 0; pf < 4; ++pf) {
            float* op = out + ((obase + (of << 4)) << 12) + hwb + (pf << 4) + (lane & 15);
#pragma unroll
            for (int r = 0; r < 4; ++r)
                op[r << 12] = fmaxf(acc[of][pf][r], 0.f);
        }
    }
}

extern "C" void kernel_launch(void* const* d_in, const int* in_sizes, int n_in,
                              void* d_out, int out_size, void* d_ws, size_t ws_size,
                              hipStream_t stream) {
    const float* x     = (const float*)d_in[0];
    const float* shape = (const float*)d_in[1];
    const float* w_off = (const float*)d_in[2];
    const float* w_def = (const float*)d_in[3];
    float* out = (float*)d_out;

    u16* wF = (u16*)d_ws;                 // 36*256*64 bf16 = 1.18 MB
    u16* xT = wF + NGK * 256 * 64;        // 8*4*4096*64 bf16 = 16.8 MB

    kprep<<<4352, 256, 0, stream>>>(x, w_def, xT, wF);
    kmain<<<NPIX / 64, 512, 0, stream>>>(xT, shape, w_off, wF, out);
}

// Round 12
// 76.254 us; speedup vs baseline: 1.5504x; 1.0072x over previous
//
#include <hip/hip_runtime.h>
#include <hip/hip_bf16.h>

// FeatureAdaption on MI355X: offset = shape @ w_off (1x1), DCNv1 deform conv + ReLU.
// B=8, Cin=Cout=256, H=W=64, G=4, Cg=64, K=3, K2=9, NGK=36, NPIX=32768.
// kprep: channels-last bf16 xT[b][g][hw][c] + fragment-major bf16 weights wF.
// kmain: 256o x 64px tile, 512 blocks (2/CU), XCD-aware work permutation
// (XCD k owns batch b=k -> slab+weights fit 4MB per-XCD L2). Prologue computes
// offsets in-block; body = R8/R11 1-tap-per-barrier pipeline (wC/wN alternation).

#define NPIX 32768
#define NGK  36
#define HW   4096
#define WSTRIDE 16384   // u16 elements per tap in wF

typedef __attribute__((ext_vector_type(8))) short short8;
typedef __attribute__((ext_vector_type(4))) float f32x4;
typedef unsigned short u16;
typedef unsigned int u32;

__device__ __forceinline__ float bfu_lo(u32 u) {
    union { u32 u; float f; } cv; cv.u = u << 16; return cv.f;
}
__device__ __forceinline__ float bfu_hi(u32 u) {
    union { u32 u; float f; } cv; cv.u = u & 0xFFFF0000u; return cv.f;
}
__device__ __forceinline__ u16 f2bf(float f) {
    union { float f; u32 u; } cv;
    cv.f = f;
    u32 u = cv.u + 0x7FFFu + ((cv.u >> 16) & 1u);
    return (u16)(u >> 16);
}

// ---------------- kprep: kxt (2048) + kwb (2304) ----------------
__global__ __launch_bounds__(256) void kprep(const float* __restrict__ x,
                                             const float* __restrict__ w_def,
                                             u16* __restrict__ xT,
                                             u16* __restrict__ wF) {
    __shared__ __align__(16) float smem[64 * 65];
    int tid = threadIdx.x;
    int blk = blockIdx.x;

    if (blk < 2048) {
        // ---- kxt: x (B,256,H,W) fp32 -> xT[b][g][hw][c] bf16 ----
        float (*tile)[65] = (float (*)[65])smem;
        int bg  = blk >> 6;
        int hw0 = (blk & 63) << 6;
        int hwo = tid & 63;
#pragma unroll
        for (int i = 0; i < 16; ++i) {
            int c = (tid >> 6) + (i << 2);
            tile[c][hwo] = x[((bg << 6) + c) * HW + hw0 + hwo];
        }
        __syncthreads();
        int hw = tid >> 2;
        int cb4 = (tid & 3) << 4;
        short8 r0, r1;
#pragma unroll
        for (int j = 0; j < 8; ++j) {
            r0[j] = (short)f2bf(tile[cb4 + j][hw]);
            r1[j] = (short)f2bf(tile[cb4 + 8 + j][hw]);
        }
        u16* dst = xT + (((bg << 12) + hw0 + hw) << 6) + cb4;
        *(short8*)dst = r0;
        *(short8*)(dst + 8) = r1;
    } else {
        // ---- kwb: fragment-major weights ----
        // (gk,o,c) -> wF[gk][wid=o>>5][of=(o>>4)&1][kc=c>>5][lane=((c>>3)&3)<<4|(o&15)][j=c&7]
        int idx = (blk - 2048) * 256 + tid;
        int c = idx & 63;
        int o = (idx >> 6) & 255;
        int gk = idx >> 14;
        int g = gk / 9, k = gk - g * 9;
        float v = w_def[((o << 8) + (g << 6) + c) * 9 + k];
        int wid = o >> 5, of = (o >> 4) & 1, olo = o & 15;
        int kc = c >> 5, cgran = (c >> 3) & 3, j = c & 7;
        int lane = (cgran << 4) | olo;
        wF[(gk << 14) + (wid << 11) + (of << 10) + (kc << 9) + (lane << 3) + j] = f2bf(v);
    }
}

// ---------------- main: fused offsets + sampling + MFMA GEMM + ReLU ----------------
struct Samp {
    short8 v00, v01, v10, v11;
    float w00, w01, w10, w11;
    int dst;
};

__device__ __forceinline__ Samp sample_issue_rec(uint2 ra, float4 rw,
                                                 const u16* __restrict__ slab,
                                                 int sp, int sck) {
    Samp s;
    int a00 = ra.x & 0xFFFF, a01 = ra.x >> 16;
    int a10 = ra.y & 0xFFFF, a11 = ra.y >> 16;
    const u16* base = slab + (sck << 3);
    s.v00 = *(const short8*)(base + (a00 << 6));
    s.v01 = *(const short8*)(base + (a01 << 6));
    s.v10 = *(const short8*)(base + (a10 << 6));
    s.v11 = *(const short8*)(base + (a11 << 6));
    s.w00 = rw.x; s.w01 = rw.y; s.w10 = rw.z; s.w11 = rw.w;
    s.dst = (sp << 6) + ((sck ^ (sp & 7)) << 3);   // XOR-swizzled slot
    return s;
}

__device__ __forceinline__ void sample_finish(const Samp& s, u16* __restrict__ sVb) {
    union { short8 s8; u32 u[4]; } A, Bc, C, D;
    A.s8 = s.v00; Bc.s8 = s.v01; C.s8 = s.v10; D.s8 = s.v11;
    union { u32 u[4]; short8 s8; } R;
#pragma unroll
    for (int j = 0; j < 4; ++j) {
        float lo0 = fmaf(s.w00, bfu_lo(A.u[j]), s.w01 * bfu_lo(Bc.u[j]));
        float lo1 = fmaf(s.w10, bfu_lo(C.u[j]), s.w11 * bfu_lo(D.u[j]));
        float hi0 = fmaf(s.w00, bfu_hi(A.u[j]), s.w01 * bfu_hi(Bc.u[j]));
        float hi1 = fmaf(s.w10, bfu_hi(C.u[j]), s.w11 * bfu_hi(D.u[j]));
        __hip_bfloat162 pk = __float22bfloat162_rn(make_float2(lo0 + lo1, hi0 + hi1));
        union { __hip_bfloat162 b; u32 u; } cv; cv.b = pk;
        R.u[j] = cv.u;
    }
    *(short8*)(sVb + s.dst) = R.s8;
}

__device__ __forceinline__ void mfma_phase(const short8 wcur[4], const u16* __restrict__ Vb,
                                           int lane, f32x4 acc[2][4]) {
    __builtin_amdgcn_s_setprio(1);
#pragma unroll
    for (int kc = 0; kc < 2; ++kc) {
        int cs = ((kc << 5) + ((lane >> 4) << 3)) ^ ((lane & 7) << 3);
        short8 bfr[4];
#pragma unroll
        for (int pf = 0; pf < 4; ++pf)
            bfr[pf] = *(const short8*)(Vb + (((pf << 4) + (lane & 15)) << 6) + cs);
#pragma unroll
        for (int of = 0; of < 2; ++of)
#pragma unroll
            for (int pf = 0; pf < 4; ++pf)
                acc[of][pf] = __builtin_amdgcn_mfma_f32_16x16x32_bf16(
                    wcur[of * 2 + kc], bfr[pf], acc[of][pf], 0, 0, 0);
    }
    __builtin_amdgcn_s_setprio(0);
}

__global__ __launch_bounds__(512, 4) void kmain(
    const u16* __restrict__ xT,
    const float* __restrict__ shape,
    const float* __restrict__ w_off,
    const u16* __restrict__ wF, float* __restrict__ out)
{
    __shared__ __align__(16) u16 sV[2][4096];        // 2 x 8 KB sampled values
    __shared__ __align__(16) uint2 sRA[NGK * 64];    // packed corner addrs, 18 KB
    __shared__ __align__(16) float4 sRW[NGK * 64];   // corner weights f32, 36 KB

    int tid = threadIdx.x;
    // XCD-aware work permutation: grid 512 = 8 XCDs x 64 tiles. Dispatch
    // round-robins blockIdx across XCDs, so give XCD k the 64 tiles of b=k:
    // per-XCD L2 working set = one 2MB slab + 1.2MB weights (fits 4MB).
    int wg = ((blockIdx.x & 7) << 6) | (blockIdx.x >> 3);
    int pixbase = wg << 6;           // 64 pixels per block
    int b = pixbase >> 12;           // == blockIdx.x & 7

    int sp = tid >> 3, sck = tid & 7;        // sampling roles: 64px x 8 chunks
    int lane = tid & 63, wid = tid >> 6;     // compute roles
    int o0 = wid << 5;                       // 8 o-slices of 32

    const u16* slabB = xT + ((size_t)b << 20);
    const u16* wlbase = wF + (wid << 11) + (lane << 3);

    f32x4 acc[2][4];
#pragma unroll
    for (int i = 0; i < 2; ++i)
#pragma unroll
        for (int j = 0; j < 4; ++j)
            acc[i][j] = (f32x4){0.f, 0.f, 0.f, 0.f};

    short8 wC[4], wN[4];
    Samp s;

    // ---- prologue A: compute offsets + rec tables in-block ----
    {
        int px = tid & 63;
        int hw = (pixbase & 4095) + px;
        int h = hw >> 6, w = hw & 63;
        float sv[36];
#pragma unroll
        for (int i = 0; i < 36; ++i) sv[i] = shape[((b * 36 + i) << 12) + hw];
        int uslot = __builtin_amdgcn_readfirstlane(wid);
#pragma unroll
        for (int j = 0; j < 5; ++j) {
            int gk = uslot + (j << 3);
            if (gk < 36) {
                const float* wy = w_off + (gk * 2) * 36;
                const float* wx = wy + 36;
                float oy = 0.f, ox = 0.f;
#pragma unroll
                for (int i = 0; i < 36; ++i) { oy += sv[i] * wy[i]; ox += sv[i] * wx[i]; }
                int k = gk % 9;
                float py = oy + (float)(k / 3 - 1) + (float)h;
                float pxx = ox + (float)(k % 3 - 1) + (float)w;
                float y0f = floorf(py), x0f = floorf(pxx);
                float fy = py - y0f, fx = pxx - x0f;
                int y0 = (int)y0f, x0 = (int)x0f;
                int y1 = y0 + 1, x1 = x0 + 1;
                float vy0 = (y0 >= 0 && y0 < 64) ? 1.f : 0.f;
                float vy1 = (y1 >= 0 && y1 < 64) ? 1.f : 0.f;
                float vx0 = (x0 >= 0 && x0 < 64) ? 1.f : 0.f;
                float vx1 = (x1 >= 0 && x1 < 64) ? 1.f : 0.f;
                float w00 = (1.f - fy) * (1.f - fx) * vy0 * vx0;
                float w01 = (1.f - fy) * fx * vy0 * vx1;
                float w10 = fy * (1.f - fx) * vy1 * vx0;
                float w11 = fy * fx * vy1 * vx1;
                int yc0 = min(max(y0, 0), 63), yc1 = min(max(y1, 0), 63);
                int xc0 = min(max(x0, 0), 63), xc1 = min(max(x1, 0), 63);
                u32 A = (u32)((yc0 << 6) | xc0) | ((u32)((yc0 << 6) | xc1) << 16);
                u32 Bp = (u32)((yc1 << 6) | xc0) | ((u32)((yc1 << 6) | xc1) << 16);
                int idx = (gk << 6) + px;
                sRA[idx] = make_uint2(A, Bp);
                sRW[idx] = make_float4(w00, w01, w10, w11);
            }
        }
    }

    // weights tap 0 -> wC (independent of rec tables)
    wC[0] = *(const short8*)(wlbase);
    wC[1] = *(const short8*)(wlbase + 512);
    wC[2] = *(const short8*)(wlbase + 1024);
    wC[3] = *(const short8*)(wlbase + 1536);
    __syncthreads();   // rec tables ready

    // ---- prologue B: sample + finish tap 0 ----
    {
        Samp s0 = sample_issue_rec(sRA[sp], sRW[sp], slabB, sp, sck);
        sample_finish(s0, sV[0]);
    }
    __syncthreads();

    // body(t): weights(t+1)->WNXT; rec(t+1) from LDS; issue gathers(t+1);
    // MFMA(t) with WCUR + sV[t&1]; finish(t+1) -> sV[nb]; barrier.
#define TAP_BODY(T, WCUR, WNXT)                                                  \
    {                                                                            \
        const int t_ = (T);                                                      \
        const u16* wn = wlbase + (t_ + 1) * WSTRIDE;                             \
        WNXT[0] = *(const short8*)(wn);                                          \
        WNXT[1] = *(const short8*)(wn + 512);                                    \
        WNXT[2] = *(const short8*)(wn + 1024);                                   \
        WNXT[3] = *(const short8*)(wn + 1536);                                   \
        s = sample_issue_rec(sRA[((t_ + 1) << 6) + sp], sRW[((t_ + 1) << 6) + sp], \
                             slabB + (((t_ + 1) / 9) << 18), sp, sck);           \
        __builtin_amdgcn_sched_barrier(0);                                       \
        mfma_phase(WCUR, &sV[t_ & 1][0], lane, acc);                             \
        sample_finish(s, &sV[(t_ & 1) ^ 1][0]);                                  \
        __syncthreads();                                                         \
    }

    for (int t = 0; t < 34; t += 2) {
        TAP_BODY(t,     wC, wN)
        TAP_BODY(t + 1, wN, wC)
    }
#undef TAP_BODY

    // ---- t=34: uses wC; prefetch tap35 -> wN; finish tap35 samples ----
    {
        const u16* wn = wlbase + 35 * WSTRIDE;
        wN[0] = *(const short8*)(wn);
        wN[1] = *(const short8*)(wn + 512);
        wN[2] = *(const short8*)(wn + 1024);
        wN[3] = *(const short8*)(wn + 1536);
        s = sample_issue_rec(sRA[(35 << 6) + sp], sRW[(35 << 6) + sp],
                             slabB + (3 << 18), sp, sck);
        __builtin_amdgcn_sched_barrier(0);
        mfma_phase(wC, &sV[0][0], lane, acc);
        sample_finish(s, &sV[1][0]);
        __syncthreads();
    }
    // ---- t=35 ----
    mfma_phase(wN, &sV[1][0], lane, acc);

    // ---- epilogue: ReLU + store ----
    int hwb = pixbase & 4095;
    int obase = (b << 8) + o0 + ((lane >> 4) << 2);
#pragma unroll
    for (int of = 0; of < 2; ++of) {
#pragma unroll
        for (int pf = 0; pf < 4; ++pf) {
            float* op = out + ((obase + (of << 4)) << 12) + hwb + (pf << 4) + (lane & 15);
#pragma unroll
            for (int r = 0; r < 4; ++r)
                op[r << 12] = fmaxf(acc[of][pf][r], 0.f);
        }
    }
}

extern "C" void kernel_launch(void* const* d_in, const int* in_sizes, int n_in,
                              void* d_out, int out_size, void* d_ws, size_t ws_size,
                              hipStream_t stream) {
    const float* x     = (const float*)d_in[0];
    const float* shape = (const float*)d_in[1];
    const float* w_off = (const float*)d_in[2];
    const float* w_def = (const float*)d_in[3];
    float* out = (float*)d_out;

    u16* wF = (u16*)d_ws;                 // 36*256*64 bf16 = 1.18 MB
    u16* xT = wF + NGK * 256 * 64;        // 8*4*4096*64 bf16 = 16.8 MB

    kprep<<<4352, 256, 0, stream>>>(x, w_def, xT, wF);
    kmain<<<NPIX / 64, 512, 0, stream>>>(xT, shape, w_off, wF, out);
}

// Round 13
// 74.618 us; speedup vs baseline: 1.5844x; 1.0219x over previous
//
#include <hip/hip_runtime.h>
#include <hip/hip_bf16.h>

// FeatureAdaption on MI355X: offset = shape @ w_off (1x1), DCNv1 deform conv + ReLU.
// B=8, Cin=Cout=256, H=W=64, G=4, Cg=64, K=3, K2=9, NGK=36, NPIX=32768.
// kprep: channels-last bf16 xT[b][g][hw][c] + fragment-major bf16 weights wF.
// kmain: 256o x 64px tile, 512 blocks (2/CU), XCD-aware permutation (b=XCD).
// In-block offset computation + rec tables. Body: 1-tap bodies with T4
// counted-vmcnt raw barriers; gathers issued one FULL body ahead (issue after
// MFMA, finish after next MFMA) -- one Samp live, 4 gathers in flight across
// each barrier, no vmcnt(0) drain in the main loop.

#define NPIX 32768
#define NGK  36
#define HW   4096
#define WSTRIDE 16384   // u16 elements per tap in wF

typedef __attribute__((ext_vector_type(8))) short short8;
typedef __attribute__((ext_vector_type(4))) float f32x4;
typedef unsigned short u16;
typedef unsigned int u32;

__device__ __forceinline__ float bfu_lo(u32 u) {
    union { u32 u; float f; } cv; cv.u = u << 16; return cv.f;
}
__device__ __forceinline__ float bfu_hi(u32 u) {
    union { u32 u; float f; } cv; cv.u = u & 0xFFFF0000u; return cv.f;
}
__device__ __forceinline__ u16 f2bf(float f) {
    union { float f; u32 u; } cv;
    cv.f = f;
    u32 u = cv.u + 0x7FFFu + ((cv.u >> 16) & 1u);
    return (u16)(u >> 16);
}

// ---------------- kprep: kxt (2048) + kwb (2304) ----------------
__global__ __launch_bounds__(256) void kprep(const float* __restrict__ x,
                                             const float* __restrict__ w_def,
                                             u16* __restrict__ xT,
                                             u16* __restrict__ wF) {
    __shared__ __align__(16) float smem[64 * 65];
    int tid = threadIdx.x;
    int blk = blockIdx.x;

    if (blk < 2048) {
        // ---- kxt: x (B,256,H,W) fp32 -> xT[b][g][hw][c] bf16 ----
        float (*tile)[65] = (float (*)[65])smem;
        int bg  = blk >> 6;
        int hw0 = (blk & 63) << 6;
        int hwo = tid & 63;
#pragma unroll
        for (int i = 0; i < 16; ++i) {
            int c = (tid >> 6) + (i << 2);
            tile[c][hwo] = x[((bg << 6) + c) * HW + hw0 + hwo];
        }
        __syncthreads();
        int hw = tid >> 2;
        int cb4 = (tid & 3) << 4;
        short8 r0, r1;
#pragma unroll
        for (int j = 0; j < 8; ++j) {
            r0[j] = (short)f2bf(tile[cb4 + j][hw]);
            r1[j] = (short)f2bf(tile[cb4 + 8 + j][hw]);
        }
        u16* dst = xT + (((bg << 12) + hw0 + hw) << 6) + cb4;
        *(short8*)dst = r0;
        *(short8*)(dst + 8) = r1;
    } else {
        // ---- kwb: fragment-major weights ----
        // (gk,o,c) -> wF[gk][wid=o>>5][of=(o>>4)&1][kc=c>>5][lane=((c>>3)&3)<<4|(o&15)][j=c&7]
        int idx = (blk - 2048) * 256 + tid;
        int c = idx & 63;
        int o = (idx >> 6) & 255;
        int gk = idx >> 14;
        int g = gk / 9, k = gk - g * 9;
        float v = w_def[((o << 8) + (g << 6) + c) * 9 + k];
        int wid = o >> 5, of = (o >> 4) & 1, olo = o & 15;
        int kc = c >> 5, cgran = (c >> 3) & 3, j = c & 7;
        int lane = (cgran << 4) | olo;
        wF[(gk << 14) + (wid << 11) + (of << 10) + (kc << 9) + (lane << 3) + j] = f2bf(v);
    }
}

// ---------------- main: fused offsets + sampling + MFMA GEMM + ReLU ----------------
struct Samp {
    short8 v00, v01, v10, v11;
    float w00, w01, w10, w11;
    int dst;
};

__device__ __forceinline__ Samp sample_issue_rec(uint2 ra, float4 rw,
                                                 const u16* __restrict__ slab,
                                                 int sp, int sck) {
    Samp s;
    int a00 = ra.x & 0xFFFF, a01 = ra.x >> 16;
    int a10 = ra.y & 0xFFFF, a11 = ra.y >> 16;
    const u16* base = slab + (sck << 3);
    s.v00 = *(const short8*)(base + (a00 << 6));
    s.v01 = *(const short8*)(base + (a01 << 6));
    s.v10 = *(const short8*)(base + (a10 << 6));
    s.v11 = *(const short8*)(base + (a11 << 6));
    s.w00 = rw.x; s.w01 = rw.y; s.w10 = rw.z; s.w11 = rw.w;
    s.dst = (sp << 6) + ((sck ^ (sp & 7)) << 3);   // XOR-swizzled slot
    return s;
}

__device__ __forceinline__ void sample_finish(const Samp& s, u16* __restrict__ sVb) {
    union { short8 s8; u32 u[4]; } A, Bc, C, D;
    A.s8 = s.v00; Bc.s8 = s.v01; C.s8 = s.v10; D.s8 = s.v11;
    union { u32 u[4]; short8 s8; } R;
#pragma unroll
    for (int j = 0; j < 4; ++j) {
        float lo0 = fmaf(s.w00, bfu_lo(A.u[j]), s.w01 * bfu_lo(Bc.u[j]));
        float lo1 = fmaf(s.w10, bfu_lo(C.u[j]), s.w11 * bfu_lo(D.u[j]));
        float hi0 = fmaf(s.w00, bfu_hi(A.u[j]), s.w01 * bfu_hi(Bc.u[j]));
        float hi1 = fmaf(s.w10, bfu_hi(C.u[j]), s.w11 * bfu_hi(D.u[j]));
        __hip_bfloat162 pk = __float22bfloat162_rn(make_float2(lo0 + lo1, hi0 + hi1));
        union { __hip_bfloat162 b; u32 u; } cv; cv.b = pk;
        R.u[j] = cv.u;
    }
    *(short8*)(sVb + s.dst) = R.s8;
}

__device__ __forceinline__ void mfma_phase(const short8 wcur[4], const u16* __restrict__ Vb,
                                           int lane, f32x4 acc[2][4]) {
    __builtin_amdgcn_s_setprio(1);
#pragma unroll
    for (int kc = 0; kc < 2; ++kc) {
        int cs = ((kc << 5) + ((lane >> 4) << 3)) ^ ((lane & 7) << 3);
        short8 bfr[4];
#pragma unroll
        for (int pf = 0; pf < 4; ++pf)
            bfr[pf] = *(const short8*)(Vb + (((pf << 4) + (lane & 15)) << 6) + cs);
#pragma unroll
        for (int of = 0; of < 2; ++of)
#pragma unroll
            for (int pf = 0; pf < 4; ++pf)
                acc[of][pf] = __builtin_amdgcn_mfma_f32_16x16x32_bf16(
                    wcur[of * 2 + kc], bfr[pf], acc[of][pf], 0, 0, 0);
    }
    __builtin_amdgcn_s_setprio(0);
}

__global__ __launch_bounds__(512, 4) void kmain(
    const u16* __restrict__ xT,
    const float* __restrict__ shape,
    const float* __restrict__ w_off,
    const u16* __restrict__ wF, float* __restrict__ out)
{
    __shared__ __align__(16) u16 sV[2][4096];        // 2 x 8 KB sampled values
    __shared__ __align__(16) uint2 sRA[NGK * 64];    // packed corner addrs, 18 KB
    __shared__ __align__(16) float4 sRW[NGK * 64];   // corner weights f32, 36 KB

    int tid = threadIdx.x;
    // XCD-aware permutation: grid 512 = 8 XCDs x 64 tiles; XCD k gets batch b=k.
    int wg = ((blockIdx.x & 7) << 6) | (blockIdx.x >> 3);
    int pixbase = wg << 6;           // 64 pixels per block
    int b = pixbase >> 12;

    int sp = tid >> 3, sck = tid & 7;        // sampling roles: 64px x 8 chunks
    int lane = tid & 63, wid = tid >> 6;     // compute roles
    int o0 = wid << 5;                       // 8 o-slices of 32

    const u16* slabB = xT + ((size_t)b << 20);
    const u16* wlbase = wF + (wid << 11) + (lane << 3);

    f32x4 acc[2][4];
#pragma unroll
    for (int i = 0; i < 2; ++i)
#pragma unroll
        for (int j = 0; j < 4; ++j)
            acc[i][j] = (f32x4){0.f, 0.f, 0.f, 0.f};

    short8 wC[4], wN[4];
    Samp s;

    // ---- prologue A: compute offsets + rec tables in-block ----
    {
        int px = tid & 63;
        int hw = (pixbase & 4095) + px;
        int h = hw >> 6, w = hw & 63;
        float sv[36];
#pragma unroll
        for (int i = 0; i < 36; ++i) sv[i] = shape[((b * 36 + i) << 12) + hw];
        int uslot = __builtin_amdgcn_readfirstlane(wid);
#pragma unroll
        for (int j = 0; j < 5; ++j) {
            int gk = uslot + (j << 3);
            if (gk < 36) {
                const float* wy = w_off + (gk * 2) * 36;
                const float* wx = wy + 36;
                float oy = 0.f, ox = 0.f;
#pragma unroll
                for (int i = 0; i < 36; ++i) { oy += sv[i] * wy[i]; ox += sv[i] * wx[i]; }
                int k = gk % 9;
                float py = oy + (float)(k / 3 - 1) + (float)h;
                float pxx = ox + (float)(k % 3 - 1) + (float)w;
                float y0f = floorf(py), x0f = floorf(pxx);
                float fy = py - y0f, fx = pxx - x0f;
                int y0 = (int)y0f, x0 = (int)x0f;
                int y1 = y0 + 1, x1 = x0 + 1;
                float vy0 = (y0 >= 0 && y0 < 64) ? 1.f : 0.f;
                float vy1 = (y1 >= 0 && y1 < 64) ? 1.f : 0.f;
                float vx0 = (x0 >= 0 && x0 < 64) ? 1.f : 0.f;
                float vx1 = (x1 >= 0 && x1 < 64) ? 1.f : 0.f;
                float w00 = (1.f - fy) * (1.f - fx) * vy0 * vx0;
                float w01 = (1.f - fy) * fx * vy0 * vx1;
                float w10 = fy * (1.f - fx) * vy1 * vx0;
                float w11 = fy * fx * vy1 * vx1;
                int yc0 = min(max(y0, 0), 63), yc1 = min(max(y1, 0), 63);
                int xc0 = min(max(x0, 0), 63), xc1 = min(max(x1, 0), 63);
                u32 A = (u32)((yc0 << 6) | xc0) | ((u32)((yc0 << 6) | xc1) << 16);
                u32 Bp = (u32)((yc1 << 6) | xc0) | ((u32)((yc1 << 6) | xc1) << 16);
                int idx = (gk << 6) + px;
                sRA[idx] = make_uint2(A, Bp);
                sRW[idx] = make_float4(w00, w01, w10, w11);
            }
        }
    }

    // weights tap 0 -> wC (independent of rec tables)
    wC[0] = *(const short8*)(wlbase);
    wC[1] = *(const short8*)(wlbase + 512);
    wC[2] = *(const short8*)(wlbase + 1024);
    wC[3] = *(const short8*)(wlbase + 1536);
    __syncthreads();   // rec tables ready

    // ---- prologue B: sample + finish tap 0 -> sV[0]; issue tap 1 gathers ----
    {
        Samp s0 = sample_issue_rec(sRA[sp], sRW[sp], slabB, sp, sck);
        sample_finish(s0, sV[0]);
        s = sample_issue_rec(sRA[64 + sp], sRW[64 + sp], slabB, sp, sck);
    }
    __syncthreads();   // full drain OK in prologue

    // body(t): wload(t+1); MFMA(t); finish s(t+1) [issued previous body];
    // issue s(t+2); counted-vmcnt barrier (4 gathers stay in flight).
#define TAP_BODY(T, WCUR, WNXT)                                                  \
    {                                                                            \
        const int t_ = (T);                                                      \
        const u16* wn = wlbase + (t_ + 1) * WSTRIDE;                             \
        WNXT[0] = *(const short8*)(wn);                                          \
        WNXT[1] = *(const short8*)(wn + 512);                                    \
        WNXT[2] = *(const short8*)(wn + 1024);                                   \
        WNXT[3] = *(const short8*)(wn + 1536);                                   \
        __builtin_amdgcn_sched_barrier(0);                                       \
        mfma_phase(WCUR, &sV[t_ & 1][0], lane, acc);                             \
        sample_finish(s, &sV[(t_ & 1) ^ 1][0]);                                  \
        if (t_ + 2 < NGK)                                                        \
            s = sample_issue_rec(sRA[((t_ + 2) << 6) + sp],                      \
                                 sRW[((t_ + 2) << 6) + sp],                      \
                                 slabB + (((t_ + 2) / 9) << 18), sp, sck);       \
        asm volatile("s_waitcnt vmcnt(4) lgkmcnt(0)" ::: "memory");              \
        __builtin_amdgcn_s_barrier();                                            \
        __builtin_amdgcn_sched_barrier(0);                                       \
    }

    for (int t = 0; t < 34; t += 2) {
        TAP_BODY(t,     wC, wN)
        TAP_BODY(t + 1, wN, wC)
    }
    // body 34: loads w(35), finishes tap 35, no new issue
    TAP_BODY(34, wC, wN)
#undef TAP_BODY

    // ---- t=35 ----
    mfma_phase(wN, &sV[1][0], lane, acc);

    // ---- epilogue: ReLU + store ----
    int hwb = pixbase & 4095;
    int obase = (b << 8) + o0 + ((lane >> 4) << 2);
#pragma unroll
    for (int of = 0; of < 2; ++of) {
#pragma unroll
        for (int pf = 0; pf < 4; ++pf) {
            float* op = out + ((obase + (of << 4)) << 12) + hwb + (pf << 4) + (lane & 15);
#pragma unroll
            for (int r = 0; r < 4; ++r)
                op[r << 12] = fmaxf(acc[of][pf][r], 0.f);
        }
    }
}

extern "C" void kernel_launch(void* const* d_in, const int* in_sizes, int n_in,
                              void* d_out, int out_size, void* d_ws, size_t ws_size,
                              hipStream_t stream) {
    const float* x     = (const float*)d_in[0];
    const float* shape = (const float*)d_in[1];
    const float* w_off = (const float*)d_in[2];
    const float* w_def = (const float*)d_in[3];
    float* out = (float*)d_out;

    u16* wF = (u16*)d_ws;                 // 36*256*64 bf16 = 1.18 MB
    u16* xT = wF + NGK * 256 * 64;        // 8*4*4096*64 bf16 = 16.8 MB

    kprep<<<4352, 256, 0, stream>>>(x, w_def, xT, wF);
    kmain<<<NPIX / 64, 512, 0, stream>>>(xT, shape, w_off, wF, out);
}

// Round 15
// 74.186 us; speedup vs baseline: 1.5936x; 1.0058x over previous
//
#include <hip/hip_runtime.h>
#include <hip/hip_bf16.h>

// FeatureAdaption on MI355X: offset = shape @ w_off (1x1), DCNv1 deform conv + ReLU.
// B=8, Cin=Cout=256, H=W=64, G=4, Cg=64, K=3, K2=9, NGK=36, NPIX=32768.
// kprep: channels-last bf16 xT[b][g][hw][c] + fragment-major bf16 weights wF.
// kmain: 256o x 64px tile, 512 blocks (2/CU), XCD-aware permutation (b=XCD).
// In-block offset computation + rec tables. Body: 1-tap bodies, counted-vmcnt
// raw barriers, gathers issued one full body ahead. Interp vectorized as
// float2 [lo,hi] -> v_pk_fma_f32/v_pk_mul_f32 (bit-identical to scalar path).

#define NPIX 32768
#define NGK  36
#define HW   4096
#define WSTRIDE 16384   // u16 elements per tap in wF

typedef __attribute__((ext_vector_type(8))) short short8;
typedef __attribute__((ext_vector_type(4))) float f32x4;
typedef __attribute__((ext_vector_type(2))) float f32x2;
typedef unsigned short u16;
typedef unsigned int u32;

__device__ __forceinline__ float bfu_lo(u32 u) {
    union { u32 u; float f; } cv; cv.u = u << 16; return cv.f;
}
__device__ __forceinline__ float bfu_hi(u32 u) {
    union { u32 u; float f; } cv; cv.u = u & 0xFFFF0000u; return cv.f;
}
__device__ __forceinline__ u16 f2bf(float f) {
    union { float f; u32 u; } cv;
    cv.f = f;
    u32 u = cv.u + 0x7FFFu + ((cv.u >> 16) & 1u);
    return (u16)(u >> 16);
}

// ---------------- kprep: kxt (2048) + kwb (2304) ----------------
__global__ __launch_bounds__(256) void kprep(const float* __restrict__ x,
                                             const float* __restrict__ w_def,
                                             u16* __restrict__ xT,
                                             u16* __restrict__ wF) {
    __shared__ __align__(16) float smem[64 * 65];
    int tid = threadIdx.x;
    int blk = blockIdx.x;

    if (blk < 2048) {
        // ---- kxt: x (B,256,H,W) fp32 -> xT[b][g][hw][c] bf16 ----
        float (*tile)[65] = (float (*)[65])smem;
        int bg  = blk >> 6;
        int hw0 = (blk & 63) << 6;
        int hwo = tid & 63;
#pragma unroll
        for (int i = 0; i < 16; ++i) {
            int c = (tid >> 6) + (i << 2);
            tile[c][hwo] = x[((bg << 6) + c) * HW + hw0 + hwo];
        }
        __syncthreads();
        int hw = tid >> 2;
        int cb4 = (tid & 3) << 4;
        short8 r0, r1;
#pragma unroll
        for (int j = 0; j < 8; ++j) {
            r0[j] = (short)f2bf(tile[cb4 + j][hw]);
            r1[j] = (short)f2bf(tile[cb4 + 8 + j][hw]);
        }
        u16* dst = xT + (((bg << 12) + hw0 + hw) << 6) + cb4;
        *(short8*)dst = r0;
        *(short8*)(dst + 8) = r1;
    } else {
        // ---- kwb: fragment-major weights ----
        // (gk,o,c) -> wF[gk][wid=o>>5][of=(o>>4)&1][kc=c>>5][lane=((c>>3)&3)<<4|(o&15)][j=c&7]
        int idx = (blk - 2048) * 256 + tid;
        int c = idx & 63;
        int o = (idx >> 6) & 255;
        int gk = idx >> 14;
        int g = gk / 9, k = gk - g * 9;
        float v = w_def[((o << 8) + (g << 6) + c) * 9 + k];
        int wid = o >> 5, of = (o >> 4) & 1, olo = o & 15;
        int kc = c >> 5, cgran = (c >> 3) & 3, j = c & 7;
        int lane = (cgran << 4) | olo;
        wF[(gk << 14) + (wid << 11) + (of << 10) + (kc << 9) + (lane << 3) + j] = f2bf(v);
    }
}

// ---------------- main: fused offsets + sampling + MFMA GEMM + ReLU ----------------
struct Samp {
    short8 v00, v01, v10, v11;
    float w00, w01, w10, w11;
    int dst;
};

__device__ __forceinline__ Samp sample_issue_rec(uint2 ra, float4 rw,
                                                 const u16* __restrict__ slab,
                                                 int sp, int sck) {
    Samp s;
    int a00 = ra.x & 0xFFFF, a01 = ra.x >> 16;
    int a10 = ra.y & 0xFFFF, a11 = ra.y >> 16;
    const u16* base = slab + (sck << 3);
    s.v00 = *(const short8*)(base + (a00 << 6));
    s.v01 = *(const short8*)(base + (a01 << 6));
    s.v10 = *(const short8*)(base + (a10 << 6));
    s.v11 = *(const short8*)(base + (a11 << 6));
    s.w00 = rw.x; s.w01 = rw.y; s.w10 = rw.z; s.w11 = rw.w;
    s.dst = (sp << 6) + ((sck ^ (sp & 7)) << 3);   // XOR-swizzled slot
    return s;
}

__device__ __forceinline__ void sample_finish(const Samp& s, u16* __restrict__ sVb) {
    union { short8 s8; u32 u[4]; } A, Bc, C, D;
    A.s8 = s.v00; Bc.s8 = s.v01; C.s8 = s.v10; D.s8 = s.v11;
    union { u32 u[4]; short8 s8; } R;
#pragma unroll
    for (int j = 0; j < 4; ++j) {
        // [lo,hi] pairs as float2 -> v_pk_* packed f32 math.
        // Same per-element op sequence as the scalar path: bit-identical.
        f32x2 a2 = {bfu_lo(A.u[j]),  bfu_hi(A.u[j])};
        f32x2 b2 = {bfu_lo(Bc.u[j]), bfu_hi(Bc.u[j])};
        f32x2 c2 = {bfu_lo(C.u[j]),  bfu_hi(C.u[j])};
        f32x2 d2 = {bfu_lo(D.u[j]),  bfu_hi(D.u[j])};
        f32x2 r0 = __builtin_elementwise_fma((f32x2){s.w00, s.w00}, a2, s.w01 * b2);
        f32x2 r1 = __builtin_elementwise_fma((f32x2){s.w10, s.w10}, c2, s.w11 * d2);
        f32x2 r = r0 + r1;
        union { __hip_bfloat162 b; u32 u; } cv;
        cv.b = __float22bfloat162_rn(make_float2(r.x, r.y));
        R.u[j] = cv.u;
    }
    *(short8*)(sVb + s.dst) = R.s8;
}

__device__ __forceinline__ void mfma_phase(const short8 wcur[4], const u16* __restrict__ Vb,
                                           int lane, f32x4 acc[2][4]) {
    __builtin_amdgcn_s_setprio(1);
#pragma unroll
    for (int kc = 0; kc < 2; ++kc) {
        int cs = ((kc << 5) + ((lane >> 4) << 3)) ^ ((lane & 7) << 3);
        short8 bfr[4];
#pragma unroll
        for (int pf = 0; pf < 4; ++pf)
            bfr[pf] = *(const short8*)(Vb + (((pf << 4) + (lane & 15)) << 6) + cs);
#pragma unroll
        for (int of = 0; of < 2; ++of)
#pragma unroll
            for (int pf = 0; pf < 4; ++pf)
                acc[of][pf] = __builtin_amdgcn_mfma_f32_16x16x32_bf16(
                    wcur[of * 2 + kc], bfr[pf], acc[of][pf], 0, 0, 0);
    }
    __builtin_amdgcn_s_setprio(0);
}

__global__ __launch_bounds__(512, 4) void kmain(
    const u16* __restrict__ xT,
    const float* __restrict__ shape,
    const float* __restrict__ w_off,
    const u16* __restrict__ wF, float* __restrict__ out)
{
    __shared__ __align__(16) u16 sV[2][4096];        // 2 x 8 KB sampled values
    __shared__ __align__(16) uint2 sRA[NGK * 64];    // packed corner addrs, 18 KB
    __shared__ __align__(16) float4 sRW[NGK * 64];   // corner weights f32, 36 KB

    int tid = threadIdx.x;
    // XCD-aware permutation: grid 512 = 8 XCDs x 64 tiles; XCD k gets batch b=k.
    int wg = ((blockIdx.x & 7) << 6) | (blockIdx.x >> 3);
    int pixbase = wg << 6;           // 64 pixels per block
    int b = pixbase >> 12;

    int sp = tid >> 3, sck = tid & 7;        // sampling roles: 64px x 8 chunks
    int lane = tid & 63, wid = tid >> 6;     // compute roles
    int o0 = wid << 5;                       // 8 o-slices of 32

    const u16* slabB = xT + ((size_t)b << 20);
    const u16* wlbase = wF + (wid << 11) + (lane << 3);

    f32x4 acc[2][4];
#pragma unroll
    for (int i = 0; i < 2; ++i)
#pragma unroll
        for (int j = 0; j < 4; ++j)
            acc[i][j] = (f32x4){0.f, 0.f, 0.f, 0.f};

    short8 wC[4], wN[4];
    Samp s;

    // ---- prologue A: compute offsets + rec tables in-block ----
    {
        int px = tid & 63;
        int hw = (pixbase & 4095) + px;
        int h = hw >> 6, w = hw & 63;
        float sv[36];
#pragma unroll
        for (int i = 0; i < 36; ++i) sv[i] = shape[((b * 36 + i) << 12) + hw];
        int uslot = __builtin_amdgcn_readfirstlane(wid);
#pragma unroll
        for (int j = 0; j < 5; ++j) {
            int gk = uslot + (j << 3);
            if (gk < 36) {
                const float* wy = w_off + (gk * 2) * 36;
                const float* wx = wy + 36;
                float oy = 0.f, ox = 0.f;
#pragma unroll
                for (int i = 0; i < 36; ++i) { oy += sv[i] * wy[i]; ox += sv[i] * wx[i]; }
                int k = gk % 9;
                float py = oy + (float)(k / 3 - 1) + (float)h;
                float pxx = ox + (float)(k % 3 - 1) + (float)w;
                float y0f = floorf(py), x0f = floorf(pxx);
                float fy = py - y0f, fx = pxx - x0f;
                int y0 = (int)y0f, x0 = (int)x0f;
                int y1 = y0 + 1, x1 = x0 + 1;
                float vy0 = (y0 >= 0 && y0 < 64) ? 1.f : 0.f;
                float vy1 = (y1 >= 0 && y1 < 64) ? 1.f : 0.f;
                float vx0 = (x0 >= 0 && x0 < 64) ? 1.f : 0.f;
                float vx1 = (x1 >= 0 && x1 < 64) ? 1.f : 0.f;
                float w00 = (1.f - fy) * (1.f - fx) * vy0 * vx0;
                float w01 = (1.f - fy) * fx * vy0 * vx1;
                float w10 = fy * (1.f - fx) * vy1 * vx0;
                float w11 = fy * fx * vy1 * vx1;
                int yc0 = min(max(y0, 0), 63), yc1 = min(max(y1, 0), 63);
                int xc0 = min(max(x0, 0), 63), xc1 = min(max(x1, 0), 63);
                u32 A = (u32)((yc0 << 6) | xc0) | ((u32)((yc0 << 6) | xc1) << 16);
                u32 Bp = (u32)((yc1 << 6) | xc0) | ((u32)((yc1 << 6) | xc1) << 16);
                int idx = (gk << 6) + px;
                sRA[idx] = make_uint2(A, Bp);
                sRW[idx] = make_float4(w00, w01, w10, w11);
            }
        }
    }

    // weights tap 0 -> wC (independent of rec tables)
    wC[0] = *(const short8*)(wlbase);
    wC[1] = *(const short8*)(wlbase + 512);
    wC[2] = *(const short8*)(wlbase + 1024);
    wC[3] = *(const short8*)(wlbase + 1536);
    __syncthreads();   // rec tables ready

    // ---- prologue B: sample + finish tap 0 -> sV[0]; issue tap 1 gathers ----
    {
        Samp s0 = sample_issue_rec(sRA[sp], sRW[sp], slabB, sp, sck);
        sample_finish(s0, sV[0]);
        s = sample_issue_rec(sRA[64 + sp], sRW[64 + sp], slabB, sp, sck);
    }
    __syncthreads();   // full drain OK in prologue

    // body(t): wload(t+1); MFMA(t); finish s(t+1) [issued previous body];
    // issue s(t+2); counted-vmcnt barrier (4 gathers stay in flight).
#define TAP_BODY(T, WCUR, WNXT)                                                  \
    {                                                                            \
        const int t_ = (T);                                                      \
        const u16* wn = wlbase + (t_ + 1) * WSTRIDE;                             \
        WNXT[0] = *(const short8*)(wn);                                          \
        WNXT[1] = *(const short8*)(wn + 512);                                    \
        WNXT[2] = *(const short8*)(wn + 1024);                                   \
        WNXT[3] = *(const short8*)(wn + 1536);                                   \
        __builtin_amdgcn_sched_barrier(0);                                       \
        mfma_phase(WCUR, &sV[t_ & 1][0], lane, acc);                             \
        sample_finish(s, &sV[(t_ & 1) ^ 1][0]);                                  \
        if (t_ + 2 < NGK)                                                        \
            s = sample_issue_rec(sRA[((t_ + 2) << 6) + sp],                      \
                                 sRW[((t_ + 2) << 6) + sp],                      \
                                 slabB + (((t_ + 2) / 9) << 18), sp, sck);       \
        asm volatile("s_waitcnt vmcnt(4) lgkmcnt(0)" ::: "memory");              \
        __builtin_amdgcn_s_barrier();                                            \
        __builtin_amdgcn_sched_barrier(0);                                       \
    }

    for (int t = 0; t < 34; t += 2) {
        TAP_BODY(t,     wC, wN)
        TAP_BODY(t + 1, wN, wC)
    }
    // body 34: loads w(35), finishes tap 35, no new issue
    TAP_BODY(34, wC, wN)
#undef TAP_BODY

    // ---- t=35 ----
    mfma_phase(wN, &sV[1][0], lane, acc);

    // ---- epilogue: ReLU + store ----
    int hwb = pixbase & 4095;
    int obase = (b << 8) + o0 + ((lane >> 4) << 2);
#pragma unroll
    for (int of = 0; of < 2; ++of) {
#pragma unroll
        for (int pf = 0; pf < 4; ++pf) {
            float* op = out + ((obase + (of << 4)) << 12) + hwb + (pf << 4) + (lane & 15);
#pragma unroll
            for (int r = 0; r < 4; ++r)
                op[r << 12] = fmaxf(acc[of][pf][r], 0.f);
        }
    }
}

extern "C" void kernel_launch(void* const* d_in, const int* in_sizes, int n_in,
                              void* d_out, int out_size, void* d_ws, size_t ws_size,
                              hipStream_t stream) {
    const float* x     = (const float*)d_in[0];
    const float* shape = (const float*)d_in[1];
    const float* w_off = (const float*)d_in[2];
    const float* w_def = (const float*)d_in[3];
    float* out = (float*)d_out;

    u16* wF = (u16*)d_ws;                 // 36*256*64 bf16 = 1.18 MB
    u16* xT = wF + NGK * 256 * 64;        // 8*4*4096*64 bf16 = 16.8 MB

    kprep<<<4352, 256, 0, stream>>>(x, w_def, xT, wF);
    kmain<<<NPIX / 64, 512, 0, stream>>>(xT, shape, w_off, wF, out);
}